// Round 12
// baseline (333.957 us; speedup 1.0000x reference)
//
#include <hip/hip_runtime.h>

typedef __bf16 bf16;
typedef __bf16 bf16x4 __attribute__((ext_vector_type(4)));
typedef __bf16 bf16x8 __attribute__((ext_vector_type(8)));
typedef float f32x4 __attribute__((ext_vector_type(4)));

#define S_LEN 2048
#define HIDDEN 2048
#define NH 16
#define NKV 8
#define HD 128
#define QKV_N 4096

// partial slot: 128x128 f32 O (65536 B) + 128x{m,l} f32 (1024 B)
#define PSLOT 66560
#define NCOUNTERS 176   // bands G in [5,16) x 16 heads

__device__ __forceinline__ void async_load16(const void* g, void* l) {
  __builtin_amdgcn_global_load_lds((const __attribute__((address_space(1))) unsigned int*)g,
                                   (__attribute__((address_space(3))) unsigned int*)l,
                                   16, 0, 0);
}

// ---- DPP 16-lane (row) reductions: row == our quad domain (l15) ----
template <int C>
__device__ __forceinline__ float dpp_f(float x) {
  return __builtin_bit_cast(float, __builtin_amdgcn_mov_dpp(
      __builtin_bit_cast(int, x), C, 0xF, 0xF, true));
}
__device__ __forceinline__ float rowmax16(float x) {
  x = fmaxf(x, dpp_f<0x128>(x));  // row_ror:8
  x = fmaxf(x, dpp_f<0x124>(x));  // row_ror:4
  x = fmaxf(x, dpp_f<0x122>(x));  // row_ror:2
  x = fmaxf(x, dpp_f<0x121>(x));  // row_ror:1
  return x;
}
__device__ __forceinline__ float rowsum16(float x) {
  x += dpp_f<0x128>(x);
  x += dpp_f<0x124>(x);
  x += dpp_f<0x122>(x);
  x += dpp_f<0x121>(x);
  return x;
}

// ---------------- fp32 -> bf16 convert (single) ----------------
__global__ __launch_bounds__(256)
void cvt_f32_bf16(const float* __restrict__ src, bf16* __restrict__ dst, int n) {
  int i = (blockIdx.x * 256 + threadIdx.x) * 4;
  if (i < n) {
    float4 v = *(const float4*)(src + i);
    bf16x4 o = {(bf16)v.x, (bf16)v.y, (bf16)v.z, (bf16)v.w};
    *(bf16x4*)(dst + i) = o;
  }
}

// ---------------- fp32 -> bf16 convert (two arrays fused) + counter zeroing ----
__global__ __launch_bounds__(256)
void cvt_pair(const float* __restrict__ s1, bf16* __restrict__ d1, int n1,
              const float* __restrict__ s2, bf16* __restrict__ d2, int n2,
              int* __restrict__ counters) {
  if (blockIdx.x == 0 && threadIdx.x < NCOUNTERS) counters[threadIdx.x] = 0;
  int i = (blockIdx.x * 256 + threadIdx.x) * 4;
  const float* s;
  bf16* d;
  int j;
  if (i < n1) { s = s1; d = d1; j = i; }
  else        { s = s2; d = d2; j = i - n1; if (j >= n2) return; }
  float4 v = *(const float4*)(s + j);
  bf16x4 o = {(bf16)v.x, (bf16)v.y, (bf16)v.z, (bf16)v.w};
  *(bf16x4*)(d + j) = o;
}

// ---------------- GEMM 128x128, BK=64 (generic, used for GEMM2) ----------------
template <int WRITE_BF16>
__global__ __launch_bounds__(256)
void gemm_bt(const bf16* __restrict__ A, const bf16* __restrict__ B,
             const float* __restrict__ bias, void* __restrict__ Cout,
             int M, int N, int K) {
  __shared__ bf16 As[2][128 * 64];   // 32 KB
  __shared__ bf16 Bs[2][128 * 64];   // 32 KB
  const int tid = threadIdx.x;
  const int w = tid >> 6, lane = tid & 63;
  const int quad = lane >> 4, l15 = lane & 15;
  const int wm = w >> 1, wn = w & 1;
  const int m0 = blockIdx.y * 128, n0 = blockIdx.x * 128;

  f32x4 acc[4][4];
#pragma unroll
  for (int i = 0; i < 4; i++)
#pragma unroll
    for (int j = 0; j < 4; j++) acc[i][j] = (f32x4){0.f, 0.f, 0.f, 0.f};

  const int crow = lane >> 2;        // 0..15
  const int ccol = (lane & 3) * 8;   // 0,8,16,24

#pragma unroll
  for (int q = 0; q < 4; q++) {
    int c = w * 4 + q, rb = c >> 1, kh = c & 1;
    async_load16(A + (size_t)(m0 + rb * 16 + crow) * K + kh * 32 + ccol,
                 (char*)As[0] + c * 1024);
    async_load16(B + (size_t)(n0 + rb * 16 + crow) * K + kh * 32 + ccol,
                 (char*)Bs[0] + c * 1024);
  }

  int cur = 0;
  for (int k0 = 0; k0 < K; k0 += 64) {
    __asm__ __volatile__("s_waitcnt vmcnt(0)" ::: "memory");
    __syncthreads();
    if (k0 + 64 < K) {
#pragma unroll
      for (int q = 0; q < 4; q++) {
        int c = w * 4 + q, rb = c >> 1, kh = c & 1;
        async_load16(A + (size_t)(m0 + rb * 16 + crow) * K + k0 + 64 + kh * 32 + ccol,
                     (char*)As[cur ^ 1] + c * 1024);
        async_load16(B + (size_t)(n0 + rb * 16 + crow) * K + k0 + 64 + kh * 32 + ccol,
                     (char*)Bs[cur ^ 1] + c * 1024);
      }
    }
    bf16x8 af[4][2], bfr[4][2];
#pragma unroll
    for (int i = 0; i < 4; i++)
#pragma unroll
      for (int kk = 0; kk < 2; kk++)
        af[i][kk] = *(const bf16x8*)((const char*)As[cur] +
                                     ((wm * 4 + i) * 2 + kk) * 1024 + l15 * 64 + quad * 16);
#pragma unroll
    for (int j = 0; j < 4; j++)
#pragma unroll
      for (int kk = 0; kk < 2; kk++)
        bfr[j][kk] = *(const bf16x8*)((const char*)Bs[cur] +
                                      ((wn * 4 + j) * 2 + kk) * 1024 + l15 * 64 + quad * 16);
#pragma unroll
    for (int kk = 0; kk < 2; kk++)
#pragma unroll
      for (int i = 0; i < 4; i++)
#pragma unroll
        for (int j = 0; j < 4; j++)
          acc[i][j] = __builtin_amdgcn_mfma_f32_16x16x32_bf16(af[i][kk], bfr[j][kk],
                                                              acc[i][j], 0, 0, 0);
    cur ^= 1;
  }

#pragma unroll
  for (int i = 0; i < 4; i++) {
#pragma unroll
    for (int j = 0; j < 4; j++) {
      int col = n0 + wn * 64 + j * 16 + l15;
      float bv = bias[col];
#pragma unroll
      for (int r = 0; r < 4; r++) {
        int row = m0 + wm * 64 + i * 16 + quad * 4 + r;
        float v = acc[i][j][r] + bv;
        if (WRITE_BF16)
          ((bf16*)Cout)[(size_t)row * N + col] = (bf16)v;
        else
          ((float*)Cout)[(size_t)row * N + col] = v;
      }
    }
  }
}

// ------- GEMM1 fused: qkv = hB @ qwB^T + b, then RMSnorm+RoPE (Q/K) / transpose (V)
// Column block nb: nb<16 -> Q head nb; 16..23 -> K head nb-16; 24..31 -> V kv nb-24.
// ANTI-SPILL STRUCTURE (round-8 lesson): after the K-loop, acc+bias is handed off
// to LDS as an f32 [128][132] tile (acc dies), then a low-pressure phase does
// RMS+RoPE per (row, 64-dim half) with partner-pair groups sharing sincos.
__global__ __launch_bounds__(256)
void gemm_qkv(const bf16* __restrict__ A, const bf16* __restrict__ B,
              const float* __restrict__ bias, const int* __restrict__ idx,
              const float* __restrict__ qnw, const float* __restrict__ knw,
              const float* __restrict__ qnhw, const float* __restrict__ knhw,
              bf16* __restrict__ Qb, bf16* __restrict__ Kb, bf16* __restrict__ VT) {
  const int K = HIDDEN;
  __shared__ __align__(16) char smem[128 * 132 * 4];  // 67584 B; GEMM uses 64 KB
  char* Abase = smem;              // [2][16384 B]
  char* Bbase = smem + 32768;      // [2][16384 B]
  const int tid = threadIdx.x;
  const int w = tid >> 6, lane = tid & 63;
  const int quad = lane >> 4, l15 = lane & 15;
  const int wm = w >> 1, wn = w & 1;
  const int m0 = blockIdx.y * 128, n0 = blockIdx.x * 128;

  f32x4 acc[4][4];
#pragma unroll
  for (int i = 0; i < 4; i++)
#pragma unroll
    for (int j = 0; j < 4; j++) acc[i][j] = (f32x4){0.f, 0.f, 0.f, 0.f};

  const int crow = lane >> 2;
  const int ccol = (lane & 3) * 8;

#pragma unroll
  for (int q = 0; q < 4; q++) {
    int c = w * 4 + q, rb = c >> 1, kh = c & 1;
    async_load16(A + (size_t)(m0 + rb * 16 + crow) * K + kh * 32 + ccol,
                 Abase + c * 1024);
    async_load16(B + (size_t)(n0 + rb * 16 + crow) * K + kh * 32 + ccol,
                 Bbase + c * 1024);
  }

  int cur = 0;
  for (int k0 = 0; k0 < K; k0 += 64) {
    __asm__ __volatile__("s_waitcnt vmcnt(0)" ::: "memory");
    __syncthreads();
    if (k0 + 64 < K) {
#pragma unroll
      for (int q = 0; q < 4; q++) {
        int c = w * 4 + q, rb = c >> 1, kh = c & 1;
        async_load16(A + (size_t)(m0 + rb * 16 + crow) * K + k0 + 64 + kh * 32 + ccol,
                     Abase + (cur ^ 1) * 16384 + c * 1024);
        async_load16(B + (size_t)(n0 + rb * 16 + crow) * K + k0 + 64 + kh * 32 + ccol,
                     Bbase + (cur ^ 1) * 16384 + c * 1024);
      }
    }
    bf16x8 af[4][2], bfr[4][2];
#pragma unroll
    for (int i = 0; i < 4; i++)
#pragma unroll
      for (int kk = 0; kk < 2; kk++)
        af[i][kk] = *(const bf16x8*)(Abase + cur * 16384 +
                                     ((wm * 4 + i) * 2 + kk) * 1024 + l15 * 64 + quad * 16);
#pragma unroll
    for (int j = 0; j < 4; j++)
#pragma unroll
      for (int kk = 0; kk < 2; kk++)
        bfr[j][kk] = *(const bf16x8*)(Bbase + cur * 16384 +
                                      ((wn * 4 + j) * 2 + kk) * 1024 + l15 * 64 + quad * 16);
#pragma unroll
    for (int kk = 0; kk < 2; kk++)
#pragma unroll
      for (int i = 0; i < 4; i++)
#pragma unroll
        for (int j = 0; j < 4; j++)
          acc[i][j] = __builtin_amdgcn_mfma_f32_16x16x32_bf16(af[i][kk], bfr[j][kk],
                                                              acc[i][j], 0, 0, 0);
    cur ^= 1;
  }

  const int nb = blockIdx.x;

  if (nb >= 24) {
    // ---- V: bias + transpose-write to VT[kv][d][s] (simple epilogue, no spill) ----
    const int kv = nb - 24;
#pragma unroll
    for (int i = 0; i < 4; i++) {
#pragma unroll
      for (int j = 0; j < 4; j++) {
        const int d = wn * 64 + j * 16 + l15;
        const float bv = bias[n0 + d];
        bf16x4 o;
#pragma unroll
        for (int r = 0; r < 4; r++) o[r] = (bf16)(acc[i][j][r] + bv);
        *(bf16x4*)(VT + ((size_t)(kv * HD + d)) * S_LEN +
                   (m0 + wm * 64 + i * 16 + quad * 4)) = o;
      }
    }
    return;
  }

  // ---- Q/K phase 1: hand acc+bias off to LDS f32 tile [128][132]; acc dies here
  __syncthreads();  // all MFMA LDS reads done before overwrite
  float* tile = (float*)smem;
#pragma unroll
  for (int i = 0; i < 4; i++) {
#pragma unroll
    for (int j = 0; j < 4; j++) {
      const int col = wn * 64 + j * 16 + l15;
      const float bv = bias[n0 + col];
      const int row = wm * 64 + i * 16 + quad * 4;
#pragma unroll
      for (int r = 0; r < 4; r++)
        tile[(row + r) * 132 + col] = acc[i][j][r] + bv;
    }
  }
  __syncthreads();

  // ---- Q/K phase 2: per (row, half) RMS + RoPE, low register pressure ----
  const bool isq = (nb < 16);
  const int head = isq ? nb : nb - 16;
  const int row = tid & 127;
  const int half = tid >> 7;
  const int srow = m0 + row;
  const float* trow = tile + row * 132 + half * 64;

  float ss = 0.f;
#pragma unroll
  for (int g = 0; g < 16; g++) {
    f32x4 v = *(const f32x4*)(trow + g * 4);
    ss += v[0] * v[0] + v[1] * v[1] + v[2] * v[2] + v[3] * v[3];
  }
  const float inv = rsqrtf(ss * (1.f / 64.f) + 1e-6f);
  const float oscale = isq ? 0.12751745f : 1.0f;  // D^-0.5*log2e folded into Q
  const float* wt = (half == 0) ? (isq ? qnw : knw) : (isq ? qnhw : knhw);
  bf16* op = (isq ? Qb : Kb) + (size_t)head * S_LEN * HD + (size_t)srow * HD + half * 64;

  if (half == 0) {
    // t-section: d = g*4+e in [0,32) pairs with d+32; freq i = d; pos row 0
    const float pos = (float)idx[srow];
#pragma unroll
    for (int g = 0; g < 8; g++) {
      f32x4 a = *(const f32x4*)(trow + g * 4);
      f32x4 b = *(const f32x4*)(trow + (g + 8) * 4);
      bf16x4 oa, ob;
#pragma unroll
      for (int e = 0; e < 4; e++) {
        const int d = g * 4 + e;
        float ya = a[e] * inv * wt[d];
        float yb = b[e] * inv * wt[32 + d];
        float s_, c_;
        sincosf(pos * exp2f(-(float)d * 0.6228615177913804f), &s_, &c_);  // log2(1e6)/32
        oa[e] = (bf16)((ya * c_ - yb * s_) * oscale);
        ob[e] = (bf16)((yb * c_ + ya * s_) * oscale);
      }
      *(bf16x4*)(op + g * 4) = oa;
      *(bf16x4*)(op + 32 + g * 4) = ob;
    }
  } else {
    // hw-section: jj = g*4+e; regions: g in {0..3} (idx row 1), {8..11} (idx row 2);
    // partner group g+4 (jj+16); freq i = (g&3)*4+e
    const float p1 = (float)idx[S_LEN + srow];
    const float p2 = (float)idx[2 * S_LEN + srow];
#pragma unroll
    for (int gg = 0; gg < 8; gg++) {
      const int g = (gg < 4) ? gg : (gg + 4);
      const float pos = (gg < 4) ? p1 : p2;
      f32x4 a = *(const f32x4*)(trow + g * 4);
      f32x4 b = *(const f32x4*)(trow + (g + 4) * 4);
      bf16x4 oa, ob;
#pragma unroll
      for (int e = 0; e < 4; e++) {
        const int jj = g * 4 + e;
        const int fi = (g & 3) * 4 + e;
        float ya = a[e] * inv * wt[jj];
        float yb = b[e] * inv * wt[jj + 16];
        float s_, c_;
        sincosf(pos * exp2f(-(float)fi * 0.8304820237218406f), &s_, &c_);  // log2(1e4)/16
        oa[e] = (bf16)((ya * c_ - yb * s_) * oscale);
        ob[e] = (bf16)((yb * c_ + ya * s_) * oscale);
      }
      *(bf16x4*)(op + g * 4) = oa;
      *(bf16x4*)(op + (g + 4) * 4) = ob;
    }
  }
}

// ---------------- Flash attention: 2 Q-bands (128 rows), chunk<=11 balance ------
// 512 blocks x 256 thr (exactly 2 blocks/CU). b: head h=b&15, cid=b>>4 in [0,32):
//   cid<5   : band G=cid (rows G*128..+127), single chunk, direct bf16 write.
//   5..16   : t=cid-5,  G=5+t/2,  c=t&1   (2 chunks).
//   17..31  : t=cid-17, G=11+t/3, c=t%3   (3 chunks).
// Chunk tiles [c*11, min(c*11+11, 2G+2)). Multi-chunk bands write f32 partials
// (slot = (cid-5)*16+h); the LAST-finishing chunk of each band merges inline
// (device counter + threadfence release/acquire — cross-XCD safe, saves the
// separate attn_merge launch and overlaps merge with the attn tail).
__global__ __launch_bounds__(256)
void attn_fused(const bf16* __restrict__ Qb, const bf16* __restrict__ Kb,
                const bf16* __restrict__ VT, bf16* __restrict__ attnO,
                char* __restrict__ Opart, int* __restrict__ counters) {
  __shared__ bf16 Kbuf[2][8192];              // 16 KB x2
  __shared__ bf16 Vbuf[8192];                 // 16 KB
  __shared__ __align__(16) bf16 Ps[4][2][16][72];
  __shared__ int lastFlag;
  const int tid = threadIdx.x;
  const int w = tid >> 6, lane = tid & 63;
  const int quad = lane >> 4, l15 = lane & 15;
  const int b = blockIdx.x;
  const int h = b & 15;
  const int cid = b >> 4;
  int G, c, nc;
  if (cid < 5)       { G = cid;          c = 0;     nc = 1; }
  else if (cid < 17) { int t = cid - 5;  G = 5 + (t >> 1);  c = t & 1; nc = 2; }
  else               { int t = cid - 17; G = 11 + t / 3;    c = t % 3; nc = 3; }
  const int nT = 2 * G + 2;
  const int tBeg = c * 11;
  const int tEnd = (tBeg + 11 < nT) ? (tBeg + 11) : nT;
  const int tCap0 = 2 * G + 1;   // half 0 valid tiles: t < tCap0
  const int kv = h >> 1;
  const int qr0h[2] = {G * 128 + w * 16, G * 128 + 64 + w * 16};

  const bf16* Qg = Qb + (size_t)h * S_LEN * HD;
  const bf16* Kg = Kb + (size_t)kv * S_LEN * HD;
  const bf16* Vg = VT + (size_t)kv * HD * S_LEN;

  const bf16* ksrc = Kg + (size_t)(w * 16 + l15) * HD + quad * 8;
  const bf16* vsrc = Vg + (size_t)(2 * w * 16 + l15) * S_LEN + quad * 8;

  bf16x8 aq[2][4];
#pragma unroll
  for (int bb = 0; bb < 2; bb++)
#pragma unroll
    for (int kc = 0; kc < 4; kc++)
      aq[bb][kc] = *(const bf16x8*)(Qg + (size_t)(qr0h[bb] + l15) * HD + kc * 32 + quad * 8);

  float m2[2][4], li[2][4];
  f32x4 Oacc[2][8];
#pragma unroll
  for (int bb = 0; bb < 2; bb++) {
#pragma unroll
    for (int r = 0; r < 4; r++) { m2[bb][r] = -1e30f; li[bb][r] = 0.f; }
#pragma unroll
    for (int dt = 0; dt < 8; dt++) Oacc[bb][dt] = (f32x4){0.f, 0.f, 0.f, 0.f};
  }

#pragma unroll
  for (int kc = 0; kc < 4; kc++)
    async_load16(ksrc + (size_t)(tBeg << 6) * HD + kc * 32,
                 (char*)Kbuf[tBeg & 1] + (w * 4 + kc) * 1024);

  for (int tt = tBeg; tt < tEnd; ++tt) {
    const int t0 = tt << 6;
    const int cur = tt & 1;
    const bool more = (tt + 1 < tEnd);
    const bool do0 = (tt < tCap0);  // block-uniform
    __asm__ __volatile__("s_waitcnt vmcnt(0)" ::: "memory");
    __syncthreads();

#pragma unroll
    for (int e = 0; e < 2; e++)
#pragma unroll
      for (int half = 0; half < 2; half++)
        async_load16(vsrc + (size_t)e * 16 * S_LEN + t0 + half * 32,
                     (char*)Vbuf + (half * 8 + 2 * w + e) * 1024);
    if (more) {
#pragma unroll
      for (int kc = 0; kc < 4; kc++)
        async_load16(ksrc + (size_t)(t0 + 64) * HD + kc * 32,
                     (char*)Kbuf[cur ^ 1] + (w * 4 + kc) * 1024);
    }

#pragma unroll
    for (int bb = 0; bb < 2; bb++) {
      if (bb == 0 && !do0) continue;
      const int qr0 = qr0h[bb];
      f32x4 sacc[4];
#pragma unroll
      for (int nt = 0; nt < 4; nt++) {
        sacc[nt] = (f32x4){0.f, 0.f, 0.f, 0.f};
#pragma unroll
        for (int kc = 0; kc < 4; kc++) {
          bf16x8 bk = *(const bf16x8*)((const char*)Kbuf[cur] + (nt * 4 + kc) * 1024 + lane * 16);
          sacc[nt] = __builtin_amdgcn_mfma_f32_16x16x32_bf16(aq[bb][kc], bk, sacc[nt], 0, 0, 0);
        }
      }
      const bool full = (t0 + 64 <= qr0);
      float mxv[4];
      bool need = false;
#pragma unroll
      for (int r = 0; r < 4; r++) {
        if (!full) {
          const int mrow = qr0 + quad * 4 + r;
          const int cb = t0 + l15;
          if (cb > mrow) sacc[0][r] = -1e30f;
          if (cb + 16 > mrow) sacc[1][r] = -1e30f;
          if (cb + 32 > mrow) sacc[2][r] = -1e30f;
          if (cb + 48 > mrow) sacc[3][r] = -1e30f;
        }
        mxv[r] = rowmax16(fmaxf(fmaxf(sacc[0][r], sacc[1][r]), fmaxf(sacc[2][r], sacc[3][r])));
        need = need || (mxv[r] > m2[bb][r] + 8.f);
      }
      if (__any(need ? 1 : 0)) {
#pragma unroll
        for (int r = 0; r < 4; r++) {
          float mnew = fmaxf(m2[bb][r], mxv[r]);
          float a = exp2f(m2[bb][r] - mnew);
          li[bb][r] *= a;
#pragma unroll
          for (int dt = 0; dt < 8; dt++) Oacc[bb][dt][r] *= a;
          m2[bb][r] = mnew;
        }
      }
#pragma unroll
      for (int r = 0; r < 4; r++) {
        float p0 = exp2f(sacc[0][r] - m2[bb][r]);
        float p1 = exp2f(sacc[1][r] - m2[bb][r]);
        float p2 = exp2f(sacc[2][r] - m2[bb][r]);
        float p3 = exp2f(sacc[3][r] - m2[bb][r]);
        li[bb][r] += rowsum16((p0 + p1) + (p2 + p3));
        Ps[w][bb][quad * 4 + r][l15] = (bf16)p0;
        Ps[w][bb][quad * 4 + r][16 + l15] = (bf16)p1;
        Ps[w][bb][quad * 4 + r][32 + l15] = (bf16)p2;
        Ps[w][bb][quad * 4 + r][48 + l15] = (bf16)p3;
      }
    }
    __asm__ __volatile__("s_waitcnt lgkmcnt(0)" ::: "memory");
    if (more)
      __asm__ __volatile__("s_waitcnt vmcnt(4)" ::: "memory");
    else
      __asm__ __volatile__("s_waitcnt vmcnt(0)" ::: "memory");

#pragma unroll
    for (int bb = 0; bb < 2; bb++) {
      if (bb == 0 && !do0) continue;
#pragma unroll
      for (int half = 0; half < 2; half++) {
        bf16x8 ap = *(const bf16x8*)(&Ps[w][bb][l15][half * 32 + quad * 8]);
#pragma unroll
        for (int dt = 0; dt < 8; dt++) {
          bf16x8 bv = *(const bf16x8*)((const char*)Vbuf + (half * 8 + dt) * 1024 + lane * 16);
          Oacc[bb][dt] = __builtin_amdgcn_mfma_f32_16x16x32_bf16(ap, bv, Oacc[bb][dt], 0, 0, 0);
        }
      }
    }
  }

  if (nc > 1) {
    // ---- write f32 partials ----
    char* slot = Opart + (size_t)((cid - 5) * 16 + h) * PSLOT;
    float* Op = (float*)slot;
    float* mlp = (float*)(slot + 65536);
#pragma unroll
    for (int bb = 0; bb < 2; bb++) {
#pragma unroll
      for (int r = 0; r < 4; r++) {
        const int row = bb * 64 + w * 16 + quad * 4 + r;
#pragma unroll
        for (int dt = 0; dt < 8; dt++)
          Op[row * 128 + dt * 16 + l15] = Oacc[bb][dt][r];
        if (l15 == 0) {
          mlp[row * 2 + 0] = m2[bb][r];
          mlp[row * 2 + 1] = li[bb][r];
        }
      }
    }
    // ---- last chunk of the band merges (release/acquire via device fence) ----
    __threadfence();   // release: partial writes visible device-wide
    __syncthreads();   // all threads of this block released
    if (tid == 0) {
      int prev = atomicAdd(&counters[(G - 5) * 16 + h], 1);
      lastFlag = (prev == nc - 1) ? 1 : 0;
    }
    __syncthreads();
    if (lastFlag) {
      __threadfence();  // acquire: invalidate stale cached partials
      const int cid0 = (G <= 10) ? (5 + (G - 5) * 2) : (17 + (G - 11) * 3);
      const char* s0 = Opart + (size_t)((cid0 - 5) * 16 + h) * PSLOT;
      const char* s1 = s0 + (size_t)16 * PSLOT;
      const char* s2 = s0 + (size_t)32 * PSLOT;
      const float* O0 = (const float*)s0;
      const float* O1 = (const float*)s1;
      const float* O2 = (const float*)s2;
      const float* ML0 = (const float*)(s0 + 65536);
      const float* ML1 = (const float*)(s1 + 65536);
      const float* ML2 = (const float*)(s2 + 65536);
#pragma unroll
      for (int it = 0; it < 16; ++it) {
        int e = it * 256 + tid;
        int row = e >> 5, d = (e & 31) * 4;
        float m0 = ML0[row * 2], l0 = ML0[row * 2 + 1];
        float m1 = ML1[row * 2], l1 = ML1[row * 2 + 1];
        float m2v = -1e30f, l2v = 0.f;
        if (nc == 3) { m2v = ML2[row * 2]; l2v = ML2[row * 2 + 1]; }
        float m = fmaxf(fmaxf(m0, m1), m2v);
        float a0 = exp2f(m0 - m), a1 = exp2f(m1 - m), a2 = exp2f(m2v - m);
        float inv = 1.f / (a0 * l0 + a1 * l1 + a2 * l2v);
        f32x4 x0 = *(const f32x4*)(O0 + row * 128 + d);
        f32x4 x1 = *(const f32x4*)(O1 + row * 128 + d);
        f32x4 x2 = (f32x4){0.f, 0.f, 0.f, 0.f};
        if (nc == 3) x2 = *(const f32x4*)(O2 + row * 128 + d);
        int srow = G * 128 + row;
        bf16x4 o;
#pragma unroll
        for (int j = 0; j < 4; j++)
          o[j] = (bf16)((a0 * x0[j] + a1 * x1[j] + a2 * x2[j]) * inv);
        *(bf16x4*)(attnO + (size_t)srow * HIDDEN + h * HD + d) = o;
      }
    }
  } else {
#pragma unroll
    for (int bb = 0; bb < 2; bb++) {
#pragma unroll
      for (int r = 0; r < 4; r++) {
        float invl = 1.f / li[bb][r];
        int srow = qr0h[bb] + quad * 4 + r;
#pragma unroll
        for (int dt = 0; dt < 8; dt++)
          attnO[(size_t)srow * HIDDEN + h * HD + dt * 16 + l15] = (bf16)(Oacc[bb][dt][r] * invl);
      }
    }
  }
}

extern "C" void kernel_launch(void* const* d_in, const int* in_sizes, int n_in,
                              void* d_out, int out_size, void* d_ws, size_t ws_size,
                              hipStream_t stream) {
  const float* hidden = (const float*)d_in[0];
  const int* idx = (const int*)d_in[1];
  const float* qkv_w = (const float*)d_in[3];
  const float* qkv_b = (const float*)d_in[4];
  const float* o_w = (const float*)d_in[5];
  const float* o_b = (const float*)d_in[6];
  const float* qnw = (const float*)d_in[7];
  const float* knw = (const float*)d_in[8];
  const float* qnhw = (const float*)d_in[9];
  const float* knhw = (const float*)d_in[10];

  char* ws = (char*)d_ws;
  // layout (MiB): phase A: [0,8) hB | [8,24) qwB | [40,48) Qb | [48,52) Kb | [52,56) VT
  //               phase B (after gemm_qkv): Opart [0, 27.5) — hB and qwB dead
  //               counters at [29, 29+704B) ; [32,40) attn
  //               phase C (after attn_fused): owB [0,8) — Opart dead
  bf16* hB    = (bf16*)(ws);
  bf16* qwB   = (bf16*)(ws + (8u << 20));
  bf16* Qb    = (bf16*)(ws + (40u << 20));
  bf16* Kb    = (bf16*)(ws + (48u << 20));
  bf16* VT    = (bf16*)(ws + (52u << 20));
  char* Opart = ws;                          // 432 slots * 66560 B = 27.5 MiB
  int* counters = (int*)(ws + (29u << 20)); // 176 ints
  bf16* owB   = hB;                          // reuse after attn (cvt runs then)
  bf16* attn  = (bf16*)(ws + (32u << 20));

  cvt_pair<<<12288, 256, 0, stream>>>(hidden, hB, HIDDEN * S_LEN,
                                      qkv_w, qwB, QKV_N * HIDDEN, counters);

  gemm_qkv<<<dim3(QKV_N / 128, S_LEN / 128), 256, 0, stream>>>(
      hB, qwB, qkv_b, idx, qnw, knw, qnhw, knhw, Qb, Kb, VT);

  attn_fused<<<512, 256, 0, stream>>>(Qb, Kb, VT, attn, Opart, counters);

  cvt_f32_bf16<<<HIDDEN * HIDDEN / 1024, 256, 0, stream>>>(o_w, owB, HIDDEN * HIDDEN);

  gemm_bt<0><<<dim3(HIDDEN / 128, S_LEN / 128), 256, 0, stream>>>(
      attn, owB, o_b, (float*)d_out, S_LEN, HIDDEN, HIDDEN);
}

// Round 14
// 265.790 us; speedup vs baseline: 1.2565x; 1.2565x over previous
//
#include <hip/hip_runtime.h>

typedef __bf16 bf16;
typedef __bf16 bf16x4 __attribute__((ext_vector_type(4)));
typedef __bf16 bf16x8 __attribute__((ext_vector_type(8)));
typedef float f32x4 __attribute__((ext_vector_type(4)));

#define S_LEN 2048
#define HIDDEN 2048
#define NH 16
#define NKV 8
#define HD 128
#define QKV_N 4096

// partial slot: 128x128 f32 O (65536 B) + 128x{m,l} f32 (1024 B)
#define PSLOT 66560

__device__ __forceinline__ void async_load16(const void* g, void* l) {
  __builtin_amdgcn_global_load_lds((const __attribute__((address_space(1))) unsigned int*)g,
                                   (__attribute__((address_space(3))) unsigned int*)l,
                                   16, 0, 0);
}

// ---- DPP 16-lane (row) reductions: row == our quad domain (l15) ----
template <int C>
__device__ __forceinline__ float dpp_f(float x) {
  return __builtin_bit_cast(float, __builtin_amdgcn_mov_dpp(
      __builtin_bit_cast(int, x), C, 0xF, 0xF, true));
}
__device__ __forceinline__ float rowmax16(float x) {
  x = fmaxf(x, dpp_f<0x128>(x));  // row_ror:8
  x = fmaxf(x, dpp_f<0x124>(x));  // row_ror:4
  x = fmaxf(x, dpp_f<0x122>(x));  // row_ror:2
  x = fmaxf(x, dpp_f<0x121>(x));  // row_ror:1
  return x;
}
__device__ __forceinline__ float rowsum16(float x) {
  x += dpp_f<0x128>(x);
  x += dpp_f<0x124>(x);
  x += dpp_f<0x122>(x);
  x += dpp_f<0x121>(x);
  return x;
}

// ---------------- fp32 -> bf16 convert (two arrays fused) ----------------
__global__ __launch_bounds__(256)
void cvt_pair(const float* __restrict__ s1, bf16* __restrict__ d1, int n1,
              const float* __restrict__ s2, bf16* __restrict__ d2, int n2) {
  int i = (blockIdx.x * 256 + threadIdx.x) * 4;
  const float* s;
  bf16* d;
  int j;
  if (i < n1) { s = s1; d = d1; j = i; }
  else        { s = s2; d = d2; j = i - n1; if (j >= n2) return; }
  float4 v = *(const float4*)(s + j);
  bf16x4 o = {(bf16)v.x, (bf16)v.y, (bf16)v.z, (bf16)v.w};
  *(bf16x4*)(d + j) = o;
}

// ---------------- GEMM 128x128, BK=64 (generic, used for GEMM2) ----------------
template <int WRITE_BF16>
__global__ __launch_bounds__(256)
void gemm_bt(const bf16* __restrict__ A, const bf16* __restrict__ B,
             const float* __restrict__ bias, void* __restrict__ Cout,
             int M, int N, int K) {
  __shared__ bf16 As[2][128 * 64];   // 32 KB
  __shared__ bf16 Bs[2][128 * 64];   // 32 KB
  const int tid = threadIdx.x;
  const int w = tid >> 6, lane = tid & 63;
  const int quad = lane >> 4, l15 = lane & 15;
  const int wm = w >> 1, wn = w & 1;
  const int m0 = blockIdx.y * 128, n0 = blockIdx.x * 128;

  f32x4 acc[4][4];
#pragma unroll
  for (int i = 0; i < 4; i++)
#pragma unroll
    for (int j = 0; j < 4; j++) acc[i][j] = (f32x4){0.f, 0.f, 0.f, 0.f};

  const int crow = lane >> 2;        // 0..15
  const int ccol = (lane & 3) * 8;   // 0,8,16,24

#pragma unroll
  for (int q = 0; q < 4; q++) {
    int c = w * 4 + q, rb = c >> 1, kh = c & 1;
    async_load16(A + (size_t)(m0 + rb * 16 + crow) * K + kh * 32 + ccol,
                 (char*)As[0] + c * 1024);
    async_load16(B + (size_t)(n0 + rb * 16 + crow) * K + kh * 32 + ccol,
                 (char*)Bs[0] + c * 1024);
  }

  int cur = 0;
  for (int k0 = 0; k0 < K; k0 += 64) {
    __asm__ __volatile__("s_waitcnt vmcnt(0)" ::: "memory");
    __syncthreads();
    if (k0 + 64 < K) {
#pragma unroll
      for (int q = 0; q < 4; q++) {
        int c = w * 4 + q, rb = c >> 1, kh = c & 1;
        async_load16(A + (size_t)(m0 + rb * 16 + crow) * K + k0 + 64 + kh * 32 + ccol,
                     (char*)As[cur ^ 1] + c * 1024);
        async_load16(B + (size_t)(n0 + rb * 16 + crow) * K + k0 + 64 + kh * 32 + ccol,
                     (char*)Bs[cur ^ 1] + c * 1024);
      }
    }
    bf16x8 af[4][2], bfr[4][2];
#pragma unroll
    for (int i = 0; i < 4; i++)
#pragma unroll
      for (int kk = 0; kk < 2; kk++)
        af[i][kk] = *(const bf16x8*)((const char*)As[cur] +
                                     ((wm * 4 + i) * 2 + kk) * 1024 + l15 * 64 + quad * 16);
#pragma unroll
    for (int j = 0; j < 4; j++)
#pragma unroll
      for (int kk = 0; kk < 2; kk++)
        bfr[j][kk] = *(const bf16x8*)((const char*)Bs[cur] +
                                      ((wn * 4 + j) * 2 + kk) * 1024 + l15 * 64 + quad * 16);
#pragma unroll
    for (int kk = 0; kk < 2; kk++)
#pragma unroll
      for (int i = 0; i < 4; i++)
#pragma unroll
        for (int j = 0; j < 4; j++)
          acc[i][j] = __builtin_amdgcn_mfma_f32_16x16x32_bf16(af[i][kk], bfr[j][kk],
                                                              acc[i][j], 0, 0, 0);
    cur ^= 1;
  }

#pragma unroll
  for (int i = 0; i < 4; i++) {
#pragma unroll
    for (int j = 0; j < 4; j++) {
      int col = n0 + wn * 64 + j * 16 + l15;
      float bv = bias[col];
#pragma unroll
      for (int r = 0; r < 4; r++) {
        int row = m0 + wm * 64 + i * 16 + quad * 4 + r;
        float v = acc[i][j][r] + bv;
        if (WRITE_BF16)
          ((bf16*)Cout)[(size_t)row * N + col] = (bf16)v;
        else
          ((float*)Cout)[(size_t)row * N + col] = v;
      }
    }
  }
}

// ------- GEMM1 fused: qkv = hB @ qwB^T + b, then RMSnorm+RoPE (Q/K) / transpose (V)
// Column block nb: nb<16 -> Q head nb; 16..23 -> K head nb-16; 24..31 -> V kv nb-24.
// ANTI-SPILL STRUCTURE (round-8 lesson): after the K-loop, acc+bias is handed off
// to LDS as an f32 [128][132] tile (acc dies), then a low-pressure phase does
// RMS+RoPE per (row, 64-dim half) with partner-pair groups sharing sincos.
__global__ __launch_bounds__(256)
void gemm_qkv(const bf16* __restrict__ A, const bf16* __restrict__ B,
              const float* __restrict__ bias, const int* __restrict__ idx,
              const float* __restrict__ qnw, const float* __restrict__ knw,
              const float* __restrict__ qnhw, const float* __restrict__ knhw,
              bf16* __restrict__ Qb, bf16* __restrict__ Kb, bf16* __restrict__ VT) {
  const int K = HIDDEN;
  __shared__ __align__(16) char smem[128 * 132 * 4];  // 67584 B; GEMM uses 64 KB
  char* Abase = smem;              // [2][16384 B]
  char* Bbase = smem + 32768;      // [2][16384 B]
  const int tid = threadIdx.x;
  const int w = tid >> 6, lane = tid & 63;
  const int quad = lane >> 4, l15 = lane & 15;
  const int wm = w >> 1, wn = w & 1;
  const int m0 = blockIdx.y * 128, n0 = blockIdx.x * 128;

  f32x4 acc[4][4];
#pragma unroll
  for (int i = 0; i < 4; i++)
#pragma unroll
    for (int j = 0; j < 4; j++) acc[i][j] = (f32x4){0.f, 0.f, 0.f, 0.f};

  const int crow = lane >> 2;
  const int ccol = (lane & 3) * 8;

#pragma unroll
  for (int q = 0; q < 4; q++) {
    int c = w * 4 + q, rb = c >> 1, kh = c & 1;
    async_load16(A + (size_t)(m0 + rb * 16 + crow) * K + kh * 32 + ccol,
                 Abase + c * 1024);
    async_load16(B + (size_t)(n0 + rb * 16 + crow) * K + kh * 32 + ccol,
                 Bbase + c * 1024);
  }

  int cur = 0;
  for (int k0 = 0; k0 < K; k0 += 64) {
    __asm__ __volatile__("s_waitcnt vmcnt(0)" ::: "memory");
    __syncthreads();
    if (k0 + 64 < K) {
#pragma unroll
      for (int q = 0; q < 4; q++) {
        int c = w * 4 + q, rb = c >> 1, kh = c & 1;
        async_load16(A + (size_t)(m0 + rb * 16 + crow) * K + k0 + 64 + kh * 32 + ccol,
                     Abase + (cur ^ 1) * 16384 + c * 1024);
        async_load16(B + (size_t)(n0 + rb * 16 + crow) * K + k0 + 64 + kh * 32 + ccol,
                     Bbase + (cur ^ 1) * 16384 + c * 1024);
      }
    }
    bf16x8 af[4][2], bfr[4][2];
#pragma unroll
    for (int i = 0; i < 4; i++)
#pragma unroll
      for (int kk = 0; kk < 2; kk++)
        af[i][kk] = *(const bf16x8*)(Abase + cur * 16384 +
                                     ((wm * 4 + i) * 2 + kk) * 1024 + l15 * 64 + quad * 16);
#pragma unroll
    for (int j = 0; j < 4; j++)
#pragma unroll
      for (int kk = 0; kk < 2; kk++)
        bfr[j][kk] = *(const bf16x8*)(Bbase + cur * 16384 +
                                      ((wn * 4 + j) * 2 + kk) * 1024 + l15 * 64 + quad * 16);
#pragma unroll
    for (int kk = 0; kk < 2; kk++)
#pragma unroll
      for (int i = 0; i < 4; i++)
#pragma unroll
        for (int j = 0; j < 4; j++)
          acc[i][j] = __builtin_amdgcn_mfma_f32_16x16x32_bf16(af[i][kk], bfr[j][kk],
                                                              acc[i][j], 0, 0, 0);
    cur ^= 1;
  }

  const int nb = blockIdx.x;

  if (nb >= 24) {
    // ---- V: bias + transpose-write to VT[kv][d][s] (simple epilogue, no spill) ----
    const int kv = nb - 24;
#pragma unroll
    for (int i = 0; i < 4; i++) {
#pragma unroll
      for (int j = 0; j < 4; j++) {
        const int d = wn * 64 + j * 16 + l15;
        const float bv = bias[n0 + d];
        bf16x4 o;
#pragma unroll
        for (int r = 0; r < 4; r++) o[r] = (bf16)(acc[i][j][r] + bv);
        *(bf16x4*)(VT + ((size_t)(kv * HD + d)) * S_LEN +
                   (m0 + wm * 64 + i * 16 + quad * 4)) = o;
      }
    }
    return;
  }

  // ---- Q/K phase 1: hand acc+bias off to LDS f32 tile [128][132]; acc dies here
  __syncthreads();  // all MFMA LDS reads done before overwrite
  float* tile = (float*)smem;
#pragma unroll
  for (int i = 0; i < 4; i++) {
#pragma unroll
    for (int j = 0; j < 4; j++) {
      const int col = wn * 64 + j * 16 + l15;
      const float bv = bias[n0 + col];
      const int row = wm * 64 + i * 16 + quad * 4;
#pragma unroll
      for (int r = 0; r < 4; r++)
        tile[(row + r) * 132 + col] = acc[i][j][r] + bv;
    }
  }
  __syncthreads();

  // ---- Q/K phase 2: per (row, half) RMS + RoPE, low register pressure ----
  const bool isq = (nb < 16);
  const int head = isq ? nb : nb - 16;
  const int row = tid & 127;
  const int half = tid >> 7;
  const int srow = m0 + row;
  const float* trow = tile + row * 132 + half * 64;

  float ss = 0.f;
#pragma unroll
  for (int g = 0; g < 16; g++) {
    f32x4 v = *(const f32x4*)(trow + g * 4);
    ss += v[0] * v[0] + v[1] * v[1] + v[2] * v[2] + v[3] * v[3];
  }
  const float inv = rsqrtf(ss * (1.f / 64.f) + 1e-6f);
  const float oscale = isq ? 0.12751745f : 1.0f;  // D^-0.5*log2e folded into Q
  const float* wt = (half == 0) ? (isq ? qnw : knw) : (isq ? qnhw : knhw);
  bf16* op = (isq ? Qb : Kb) + (size_t)head * S_LEN * HD + (size_t)srow * HD + half * 64;

  if (half == 0) {
    // t-section: d = g*4+e in [0,32) pairs with d+32; freq i = d; pos row 0
    const float pos = (float)idx[srow];
#pragma unroll
    for (int g = 0; g < 8; g++) {
      f32x4 a = *(const f32x4*)(trow + g * 4);
      f32x4 b = *(const f32x4*)(trow + (g + 8) * 4);
      bf16x4 oa, ob;
#pragma unroll
      for (int e = 0; e < 4; e++) {
        const int d = g * 4 + e;
        float ya = a[e] * inv * wt[d];
        float yb = b[e] * inv * wt[32 + d];
        float s_, c_;
        sincosf(pos * exp2f(-(float)d * 0.6228615177913804f), &s_, &c_);  // log2(1e6)/32
        oa[e] = (bf16)((ya * c_ - yb * s_) * oscale);
        ob[e] = (bf16)((yb * c_ + ya * s_) * oscale);
      }
      *(bf16x4*)(op + g * 4) = oa;
      *(bf16x4*)(op + 32 + g * 4) = ob;
    }
  } else {
    // hw-section: jj = g*4+e; regions: g in {0..3} (idx row 1), {8..11} (idx row 2);
    // partner group g+4 (jj+16); freq i = (g&3)*4+e
    const float p1 = (float)idx[S_LEN + srow];
    const float p2 = (float)idx[2 * S_LEN + srow];
#pragma unroll
    for (int gg = 0; gg < 8; gg++) {
      const int g = (gg < 4) ? gg : (gg + 4);
      const float pos = (gg < 4) ? p1 : p2;
      f32x4 a = *(const f32x4*)(trow + g * 4);
      f32x4 b = *(const f32x4*)(trow + (g + 4) * 4);
      bf16x4 oa, ob;
#pragma unroll
      for (int e = 0; e < 4; e++) {
        const int jj = g * 4 + e;
        const int fi = (g & 3) * 4 + e;
        float ya = a[e] * inv * wt[jj];
        float yb = b[e] * inv * wt[jj + 16];
        float s_, c_;
        sincosf(pos * exp2f(-(float)fi * 0.8304820237218406f), &s_, &c_);  // log2(1e4)/16
        oa[e] = (bf16)((ya * c_ - yb * s_) * oscale);
        ob[e] = (bf16)((yb * c_ + ya * s_) * oscale);
      }
      *(bf16x4*)(op + g * 4) = oa;
      *(bf16x4*)(op + (g + 4) * 4) = ob;
    }
  }
}

// ---------------- Flash attention: 2 Q-bands (128 rows), chunk<=11 balance ------
// 512 blocks x 256 thr (exactly 2 blocks/CU). b: head h=b&15, cid=b>>4 in [0,32):
//   cid<5   : band G=cid (rows G*128..+127), single chunk, direct bf16 write.
//   5..16   : t=cid-5,  G=5+t/2,  c=t&1   (2 chunks).
//   17..31  : t=cid-17, G=11+t/3, c=t%3   (3 chunks).
// Chunk tiles [c*11, min(c*11+11, 2G+2)). Multi-chunk bands write f32 partials
// (slot = (cid-5)*16+h), merged by merge_cvt. Inner loop = R11-verified.
// (R12 lesson: inline merge via device fences trashed L2 for co-resident
//  blocks — FETCH doubled, 2.3x slower. Separate merge kernel is the way.)
__global__ __launch_bounds__(256)
void attn_fused(const bf16* __restrict__ Qb, const bf16* __restrict__ Kb,
                const bf16* __restrict__ VT, bf16* __restrict__ attnO,
                char* __restrict__ Opart) {
  __shared__ bf16 Kbuf[2][8192];              // 16 KB x2
  __shared__ bf16 Vbuf[8192];                 // 16 KB
  __shared__ __align__(16) bf16 Ps[4][2][16][72];
  const int tid = threadIdx.x;
  const int w = tid >> 6, lane = tid & 63;
  const int quad = lane >> 4, l15 = lane & 15;
  const int b = blockIdx.x;
  const int h = b & 15;
  const int cid = b >> 4;
  int G, c, nc;
  if (cid < 5)       { G = cid;          c = 0;     nc = 1; }
  else if (cid < 17) { int t = cid - 5;  G = 5 + (t >> 1);  c = t & 1; nc = 2; }
  else               { int t = cid - 17; G = 11 + t / 3;    c = t % 3; nc = 3; }
  const int nT = 2 * G + 2;
  const int tBeg = c * 11;
  const int tEnd = (tBeg + 11 < nT) ? (tBeg + 11) : nT;
  const int tCap0 = 2 * G + 1;   // half 0 valid tiles: t < tCap0
  const int kv = h >> 1;
  const int qr0h[2] = {G * 128 + w * 16, G * 128 + 64 + w * 16};

  const bf16* Qg = Qb + (size_t)h * S_LEN * HD;
  const bf16* Kg = Kb + (size_t)kv * S_LEN * HD;
  const bf16* Vg = VT + (size_t)kv * HD * S_LEN;

  const bf16* ksrc = Kg + (size_t)(w * 16 + l15) * HD + quad * 8;
  const bf16* vsrc = Vg + (size_t)(2 * w * 16 + l15) * S_LEN + quad * 8;

  bf16x8 aq[2][4];
#pragma unroll
  for (int bb = 0; bb < 2; bb++)
#pragma unroll
    for (int kc = 0; kc < 4; kc++)
      aq[bb][kc] = *(const bf16x8*)(Qg + (size_t)(qr0h[bb] + l15) * HD + kc * 32 + quad * 8);

  float m2[2][4], li[2][4];
  f32x4 Oacc[2][8];
#pragma unroll
  for (int bb = 0; bb < 2; bb++) {
#pragma unroll
    for (int r = 0; r < 4; r++) { m2[bb][r] = -1e30f; li[bb][r] = 0.f; }
#pragma unroll
    for (int dt = 0; dt < 8; dt++) Oacc[bb][dt] = (f32x4){0.f, 0.f, 0.f, 0.f};
  }

#pragma unroll
  for (int kc = 0; kc < 4; kc++)
    async_load16(ksrc + (size_t)(tBeg << 6) * HD + kc * 32,
                 (char*)Kbuf[tBeg & 1] + (w * 4 + kc) * 1024);

  for (int tt = tBeg; tt < tEnd; ++tt) {
    const int t0 = tt << 6;
    const int cur = tt & 1;
    const bool more = (tt + 1 < tEnd);
    const bool do0 = (tt < tCap0);  // block-uniform
    __asm__ __volatile__("s_waitcnt vmcnt(0)" ::: "memory");
    __syncthreads();

#pragma unroll
    for (int e = 0; e < 2; e++)
#pragma unroll
      for (int half = 0; half < 2; half++)
        async_load16(vsrc + (size_t)e * 16 * S_LEN + t0 + half * 32,
                     (char*)Vbuf + (half * 8 + 2 * w + e) * 1024);
    if (more) {
#pragma unroll
      for (int kc = 0; kc < 4; kc++)
        async_load16(ksrc + (size_t)(t0 + 64) * HD + kc * 32,
                     (char*)Kbuf[cur ^ 1] + (w * 4 + kc) * 1024);
    }

#pragma unroll
    for (int bb = 0; bb < 2; bb++) {
      if (bb == 0 && !do0) continue;
      const int qr0 = qr0h[bb];
      f32x4 sacc[4];
#pragma unroll
      for (int nt = 0; nt < 4; nt++) {
        sacc[nt] = (f32x4){0.f, 0.f, 0.f, 0.f};
#pragma unroll
        for (int kc = 0; kc < 4; kc++) {
          bf16x8 bk = *(const bf16x8*)((const char*)Kbuf[cur] + (nt * 4 + kc) * 1024 + lane * 16);
          sacc[nt] = __builtin_amdgcn_mfma_f32_16x16x32_bf16(aq[bb][kc], bk, sacc[nt], 0, 0, 0);
        }
      }
      const bool full = (t0 + 64 <= qr0);
      float mxv[4];
      bool need = false;
#pragma unroll
      for (int r = 0; r < 4; r++) {
        if (!full) {
          const int mrow = qr0 + quad * 4 + r;
          const int cb = t0 + l15;
          if (cb > mrow) sacc[0][r] = -1e30f;
          if (cb + 16 > mrow) sacc[1][r] = -1e30f;
          if (cb + 32 > mrow) sacc[2][r] = -1e30f;
          if (cb + 48 > mrow) sacc[3][r] = -1e30f;
        }
        mxv[r] = rowmax16(fmaxf(fmaxf(sacc[0][r], sacc[1][r]), fmaxf(sacc[2][r], sacc[3][r])));
        need = need || (mxv[r] > m2[bb][r] + 8.f);
      }
      if (__any(need ? 1 : 0)) {
#pragma unroll
        for (int r = 0; r < 4; r++) {
          float mnew = fmaxf(m2[bb][r], mxv[r]);
          float a = exp2f(m2[bb][r] - mnew);
          li[bb][r] *= a;
#pragma unroll
          for (int dt = 0; dt < 8; dt++) Oacc[bb][dt][r] *= a;
          m2[bb][r] = mnew;
        }
      }
#pragma unroll
      for (int r = 0; r < 4; r++) {
        float p0 = exp2f(sacc[0][r] - m2[bb][r]);
        float p1 = exp2f(sacc[1][r] - m2[bb][r]);
        float p2 = exp2f(sacc[2][r] - m2[bb][r]);
        float p3 = exp2f(sacc[3][r] - m2[bb][r]);
        li[bb][r] += rowsum16((p0 + p1) + (p2 + p3));
        Ps[w][bb][quad * 4 + r][l15] = (bf16)p0;
        Ps[w][bb][quad * 4 + r][16 + l15] = (bf16)p1;
        Ps[w][bb][quad * 4 + r][32 + l15] = (bf16)p2;
        Ps[w][bb][quad * 4 + r][48 + l15] = (bf16)p3;
      }
    }
    __asm__ __volatile__("s_waitcnt lgkmcnt(0)" ::: "memory");
    if (more)
      __asm__ __volatile__("s_waitcnt vmcnt(4)" ::: "memory");
    else
      __asm__ __volatile__("s_waitcnt vmcnt(0)" ::: "memory");

#pragma unroll
    for (int bb = 0; bb < 2; bb++) {
      if (bb == 0 && !do0) continue;
#pragma unroll
      for (int half = 0; half < 2; half++) {
        bf16x8 ap = *(const bf16x8*)(&Ps[w][bb][l15][half * 32 + quad * 8]);
#pragma unroll
        for (int dt = 0; dt < 8; dt++) {
          bf16x8 bv = *(const bf16x8*)((const char*)Vbuf + (half * 8 + dt) * 1024 + lane * 16);
          Oacc[bb][dt] = __builtin_amdgcn_mfma_f32_16x16x32_bf16(ap, bv, Oacc[bb][dt], 0, 0, 0);
        }
      }
    }
  }

  if (nc > 1) {
    char* slot = Opart + (size_t)((cid - 5) * 16 + h) * PSLOT;
    float* Op = (float*)slot;
    float* mlp = (float*)(slot + 65536);
#pragma unroll
    for (int bb = 0; bb < 2; bb++) {
#pragma unroll
      for (int r = 0; r < 4; r++) {
        const int row = bb * 64 + w * 16 + quad * 4 + r;
#pragma unroll
        for (int dt = 0; dt < 8; dt++)
          Op[row * 128 + dt * 16 + l15] = Oacc[bb][dt][r];
        if (l15 == 0) {
          mlp[row * 2 + 0] = m2[bb][r];
          mlp[row * 2 + 1] = li[bb][r];
        }
      }
    }
  } else {
#pragma unroll
    for (int bb = 0; bb < 2; bb++) {
#pragma unroll
      for (int r = 0; r < 4; r++) {
        float invl = 1.f / li[bb][r];
        int srow = qr0h[bb] + quad * 4 + r;
#pragma unroll
        for (int dt = 0; dt < 8; dt++)
          attnO[(size_t)srow * HIDDEN + h * HD + dt * 16 + l15] = (bf16)(Oacc[bb][dt][r] * invl);
      }
    }
  }
}

// -------- merge 2-3 chunk partials (bands G in [5,16)) + o_w f32->bf16 cvt -----
// Grid 4096 x 256: every block converts a 1024-float slice of o_w into owB
// (placed in the dead Qb region); blocks 0..175 additionally merge one (G,h).
__global__ __launch_bounds__(256)
void merge_cvt(const char* __restrict__ Opart, bf16* __restrict__ attnO,
               const float* __restrict__ ow, bf16* __restrict__ owB) {
  const int t = threadIdx.x;
  // conversion slice (all blocks)
  {
    int i = (blockIdx.x * 256 + t) * 4;
    float4 v = *(const float4*)(ow + i);
    bf16x4 o = {(bf16)v.x, (bf16)v.y, (bf16)v.z, (bf16)v.w};
    *(bf16x4*)(owB + i) = o;
  }
  if (blockIdx.x >= 176) return;

  const int h = blockIdx.x & 15;
  const int bandIdx = blockIdx.x >> 4;   // 0..10
  const int G = 5 + bandIdx;
  const int nc = (G <= 10) ? 2 : 3;
  const int cid0 = (G <= 10) ? (5 + (G - 5) * 2) : (17 + (G - 11) * 3);
  const char* s0 = Opart + (size_t)((cid0 - 5) * 16 + h) * PSLOT;
  const char* s1 = s0 + (size_t)16 * PSLOT;
  const char* s2 = s0 + (size_t)32 * PSLOT;
  const float* O0 = (const float*)s0;
  const float* O1 = (const float*)s1;
  const float* O2 = (const float*)s2;
  const float* ML0 = (const float*)(s0 + 65536);
  const float* ML1 = (const float*)(s1 + 65536);
  const float* ML2 = (const float*)(s2 + 65536);
#pragma unroll
  for (int it = 0; it < 16; ++it) {
    int e = it * 256 + t;
    int row = e >> 5, d = (e & 31) * 4;
    float m0 = ML0[row * 2], l0 = ML0[row * 2 + 1];
    float m1 = ML1[row * 2], l1 = ML1[row * 2 + 1];
    float m2v = -1e30f, l2v = 0.f;
    if (nc == 3) { m2v = ML2[row * 2]; l2v = ML2[row * 2 + 1]; }
    float m = fmaxf(fmaxf(m0, m1), m2v);
    float a0 = exp2f(m0 - m), a1 = exp2f(m1 - m), a2 = exp2f(m2v - m);
    float inv = 1.f / (a0 * l0 + a1 * l1 + a2 * l2v);
    f32x4 x0 = *(const f32x4*)(O0 + row * 128 + d);
    f32x4 x1 = *(const f32x4*)(O1 + row * 128 + d);
    f32x4 x2 = (f32x4){0.f, 0.f, 0.f, 0.f};
    if (nc == 3) x2 = *(const f32x4*)(O2 + row * 128 + d);
    int srow = G * 128 + row;
    bf16x4 o;
#pragma unroll
    for (int j = 0; j < 4; j++)
      o[j] = (bf16)((a0 * x0[j] + a1 * x1[j] + a2 * x2[j]) * inv);
    *(bf16x4*)(attnO + (size_t)srow * HIDDEN + h * HD + d) = o;
  }
}

extern "C" void kernel_launch(void* const* d_in, const int* in_sizes, int n_in,
                              void* d_out, int out_size, void* d_ws, size_t ws_size,
                              hipStream_t stream) {
  const float* hidden = (const float*)d_in[0];
  const int* idx = (const int*)d_in[1];
  const float* qkv_w = (const float*)d_in[3];
  const float* qkv_b = (const float*)d_in[4];
  const float* o_w = (const float*)d_in[5];
  const float* o_b = (const float*)d_in[6];
  const float* qnw = (const float*)d_in[7];
  const float* knw = (const float*)d_in[8];
  const float* qnhw = (const float*)d_in[9];
  const float* knhw = (const float*)d_in[10];

  char* ws = (char*)d_ws;
  // layout (MiB): phase A: [0,8) hB | [8,24) qwB | [40,48) Qb | [48,52) Kb | [52,56) VT
  //               phase B (after gemm_qkv): Opart [0, 28.75) — hB and qwB dead
  //               [32,40) attn
  //               phase C (merge_cvt, after attn): owB at [40,48) — Qb dead
  bf16* hB    = (bf16*)(ws);
  bf16* qwB   = (bf16*)(ws + (8u << 20));
  bf16* Qb    = (bf16*)(ws + (40u << 20));
  bf16* Kb    = (bf16*)(ws + (48u << 20));
  bf16* VT    = (bf16*)(ws + (52u << 20));
  char* Opart = ws;                          // 432 slots * 66560 B = 28.75 MiB
  bf16* owB   = (bf16*)(ws + (40u << 20));   // reuse Qb region after attn
  bf16* attn  = (bf16*)(ws + (32u << 20));

  cvt_pair<<<12288, 256, 0, stream>>>(hidden, hB, HIDDEN * S_LEN,
                                      qkv_w, qwB, QKV_N * HIDDEN);

  gemm_qkv<<<dim3(QKV_N / 128, S_LEN / 128), 256, 0, stream>>>(
      hB, qwB, qkv_b, idx, qnw, knw, qnhw, knhw, Qb, Kb, VT);

  attn_fused<<<512, 256, 0, stream>>>(Qb, Kb, VT, attn, Opart);

  merge_cvt<<<4096, 256, 0, stream>>>(Opart, attn, o_w, owB);

  gemm_bt<0><<<dim3(HIDDEN / 128, S_LEN / 128), 256, 0, stream>>>(
      attn, owB, o_b, (float*)d_out, S_LEN, HIDDEN, HIDDEN);
}